// Round 1
// baseline (936.343 us; speedup 1.0000x reference)
//
#include <hip/hip_runtime.h>

#define N_DIM 8192
#define E_DIM 4096

using short8 = __attribute__((ext_vector_type(8))) short;
using f32x4  = __attribute__((ext_vector_type(4))) float;

// float -> bf16 bits, round-to-nearest-even (inputs are finite)
__device__ __forceinline__ unsigned short f2bf(float f) {
  union { float f; unsigned int u; } v; v.f = f;
  unsigned int r = v.u + 0x7FFFu + ((v.u >> 16) & 1u);
  return (unsigned short)(r >> 16);
}

// async global->LDS, 16B per lane. LDS dest is wave-uniform base + lane*16.
__device__ __forceinline__ void async16(const void* g, void* l) {
  __builtin_amdgcn_global_load_lds(
      (const __attribute__((address_space(1))) unsigned int*)g,
      (__attribute__((address_space(3))) unsigned int*)l, 16, 0, 0);
}

// ---------------- kernel 1: d = rsqrt(H @ W), one wave per row ----------------
__global__ __launch_bounds__(256) void k_rowdeg(const float* __restrict__ H,
                                                const float* __restrict__ W,
                                                float* __restrict__ d) {
  const int row  = blockIdx.x * 4 + (threadIdx.x >> 6);
  const int lane = threadIdx.x & 63;
  const float* hrow = H + (size_t)row * E_DIM;
  float s = 0.f;
  for (int e = lane * 4; e < E_DIM; e += 64 * 4) {
    float4 h = *reinterpret_cast<const float4*>(hrow + e);
    float4 w = *reinterpret_cast<const float4*>(W + e);
    s += h.x * w.x + h.y * w.y + h.z * w.z + h.w * w.w;
  }
#pragma unroll
  for (int off = 32; off; off >>= 1) s += __shfl_down(s, off);
  if (lane == 0) d[row] = rsqrtf(s);
}

// ---------------- kernel 2: A_bf16[i][e] = bf16(d_i * H[i][e]) ----------------
__global__ __launch_bounds__(256) void k_makeA(const float* __restrict__ H,
                                               const float* __restrict__ d,
                                               unsigned short* __restrict__ A) {
  const size_t idx = ((size_t)blockIdx.x * 256 + threadIdx.x) * 4;
  const int row = (int)(idx >> 12);  // E_DIM = 4096 = 2^12
  const float dv = d[row];
  float4 h = *reinterpret_cast<const float4*>(H + idx);
  ushort4 o;
  o.x = f2bf(h.x * dv);
  o.y = f2bf(h.y * dv);
  o.z = f2bf(h.z * dv);
  o.w = f2bf(h.w * dv);
  *reinterpret_cast<ushort4*>(A + idx) = o;
}

// ------- kernel 3: Bt_bf16[j][e] = bf16(W_e * invDE_HT[e][j] * d_j) (transpose) -------
__global__ __launch_bounds__(256) void k_makeB(const float* __restrict__ R,
                                               const float* __restrict__ W,
                                               const float* __restrict__ d,
                                               unsigned short* __restrict__ Bt) {
  __shared__ float tile[32][33];
  const int j0 = blockIdx.x * 32;  // N dim
  const int e0 = blockIdx.y * 32;  // E dim
  const int tx = threadIdx.x;      // 0..31
  const int ty = threadIdx.y;      // 0..7
#pragma unroll
  for (int i = 0; i < 32; i += 8)
    tile[ty + i][tx] = R[(size_t)(e0 + ty + i) * N_DIM + j0 + tx];
  __syncthreads();
  const float we = W[e0 + tx];
#pragma unroll
  for (int i = 0; i < 32; i += 8) {
    const int j = j0 + ty + i;
    float v = tile[tx][ty + i] * we * d[j];
    Bt[(size_t)j * E_DIM + e0 + tx] = f2bf(v);
  }
}

// ---------------- kernel 4: C = A_bf16 @ Bt_bf16^T  (m97 structure) ----------------
// 128x128 tile, BK=64, 256 threads (4 waves, 2x2), each wave: 64x64 out (4x4 frags)
__global__ __launch_bounds__(256) void k_gemm(const unsigned short* __restrict__ A,
                                              const unsigned short* __restrict__ B,
                                              float* __restrict__ C) {
  __shared__ unsigned short Alds[128 * 64];
  __shared__ unsigned short Blds[128 * 64];

  // bijective XCD swizzle (gridDim.x = 4096, divisible by 8)
  const int bid   = blockIdx.x;
  const int chunk = gridDim.x >> 3;
  const int swz   = (bid & 7) * chunk + (bid >> 3);
  const int tm = swz >> 6;
  const int tn = swz & 63;
  const size_t rowBase = (size_t)tm * 128;
  const size_t colBase = (size_t)tn * 128;

  const int t    = threadIdx.x;
  const int w    = t >> 6;
  const int lane = t & 63;
  const int r0 = t >> 3;        // staging row within 32-row slab
  const int c0 = (t & 7) * 8;   // staging col (elements)

  const unsigned short* Ag = A + (rowBase + r0) * E_DIM + c0;
  const unsigned short* Bg = B + (colBase + r0) * E_DIM + c0;
  unsigned short* Al = &Alds[w * 512];
  unsigned short* Bl = &Blds[w * 512];

  const int wr = (w >> 1) * 64;
  const int wc = (w & 1) * 64;

  f32x4 acc[4][4] = {};

  for (int kt = 0; kt < E_DIM; kt += 64) {
    __syncthreads();  // previous compute done before LDS overwrite
#pragma unroll
    for (int i = 0; i < 4; ++i) {
      async16(Ag + (size_t)i * 32 * E_DIM + kt, Al + i * 2048);
      async16(Bg + (size_t)i * 32 * E_DIM + kt, Bl + i * 2048);
    }
    __syncthreads();  // compiler drains vmcnt(0) before barrier -> tile ready
#pragma unroll
    for (int kk = 0; kk < 64; kk += 32) {
      short8 af[4], bf[4];
      const int colo = kk + (lane >> 4) * 8;
#pragma unroll
      for (int m = 0; m < 4; ++m)
        af[m] = *(const short8*)&Alds[(wr + m * 16 + (lane & 15)) * 64 + colo];
#pragma unroll
      for (int n = 0; n < 4; ++n)
        bf[n] = *(const short8*)&Blds[(wc + n * 16 + (lane & 15)) * 64 + colo];
#pragma unroll
      for (int m = 0; m < 4; ++m)
#pragma unroll
        for (int n = 0; n < 4; ++n)
          acc[m][n] = __builtin_amdgcn_mfma_f32_16x16x32_bf16(af[m], bf[n], acc[m][n], 0, 0, 0);
    }
  }

  // epilogue: C/D layout col=lane&15, row=(lane>>4)*4+reg (HW-verified)
#pragma unroll
  for (int m = 0; m < 4; ++m)
#pragma unroll
    for (int n = 0; n < 4; ++n)
#pragma unroll
      for (int r = 0; r < 4; ++r) {
        size_t row = rowBase + wr + m * 16 + (lane >> 4) * 4 + r;
        size_t col = colBase + wc + n * 16 + (lane & 15);
        C[row * N_DIM + col] = acc[m][n][r];
      }
}

extern "C" void kernel_launch(void* const* d_in, const int* in_sizes, int n_in,
                              void* d_out, int out_size, void* d_ws, size_t ws_size,
                              hipStream_t stream) {
  const float* H = (const float*)d_in[0];        // [N, E]
  const float* R = (const float*)d_in[1];        // [E, N] = invDE_HT
  const float* W = (const float*)d_in[2];        // [E]
  float* C = (float*)d_out;                      // [N, N]

  char* ws = (char*)d_ws;
  float* d            = (float*)ws;                                   // 32 KB
  unsigned short* Abf = (unsigned short*)(ws + 32768);                // 64 MB
  unsigned short* Bbf = (unsigned short*)(ws + 32768 + (size_t)N_DIM * E_DIM * 2);

  k_rowdeg<<<N_DIM / 4, 256, 0, stream>>>(H, W, d);
  k_makeA<<<(int)(((size_t)N_DIM * E_DIM / 4) / 256), 256, 0, stream>>>(H, d, Abf);
  k_makeB<<<dim3(N_DIM / 32, E_DIM / 32), dim3(32, 8), 0, stream>>>(R, W, d, Bbf);
  k_gemm<<<(N_DIM / 128) * (N_DIM / 128), 256, 0, stream>>>(Abf, Bbf, C);
}

// Round 2
// 581.310 us; speedup vs baseline: 1.6107x; 1.6107x over previous
//
#include <hip/hip_runtime.h>

#define N_DIM 8192
#define E_DIM 4096
#define NT    64   // K-tiles of 64

using short8 = __attribute__((ext_vector_type(8))) short;
using f32x4  = __attribute__((ext_vector_type(4))) float;

__device__ __forceinline__ unsigned short f2bf(float f) {
  union { float f; unsigned int u; } v; v.f = f;
  unsigned int r = v.u + 0x7FFFu + ((v.u >> 16) & 1u);
  return (unsigned short)(r >> 16);
}

__device__ __forceinline__ void async16(const void* g, void* l) {
  __builtin_amdgcn_global_load_lds(
      (const __attribute__((address_space(1))) unsigned int*)g,
      (__attribute__((address_space(3))) unsigned int*)l, 16, 0, 0);
}

// ---------------- kernel 1: d = rsqrt(H @ W), one wave per row ----------------
__global__ __launch_bounds__(256) void k_rowdeg(const float* __restrict__ H,
                                                const float* __restrict__ W,
                                                float* __restrict__ d) {
  const int row  = blockIdx.x * 4 + (threadIdx.x >> 6);
  const int lane = threadIdx.x & 63;
  const float* hrow = H + (size_t)row * E_DIM;
  float s = 0.f;
  for (int e = lane * 4; e < E_DIM; e += 64 * 4) {
    float4 h = *reinterpret_cast<const float4*>(hrow + e);
    float4 w = *reinterpret_cast<const float4*>(W + e);
    s += h.x * w.x + h.y * w.y + h.z * w.z + h.w * w.w;
  }
#pragma unroll
  for (int off = 32; off; off >>= 1) s += __shfl_down(s, off);
  if (lane == 0) d[row] = rsqrtf(s);
}

// ---------------- kernel 2: A_bf16[i][e] = bf16(d_i * H[i][e]) ----------------
__global__ __launch_bounds__(256) void k_makeA(const float* __restrict__ H,
                                               const float* __restrict__ d,
                                               unsigned short* __restrict__ A) {
  const size_t idx = ((size_t)blockIdx.x * 256 + threadIdx.x) * 4;
  const int row = (int)(idx >> 12);
  const float dv = d[row];
  float4 h = *reinterpret_cast<const float4*>(H + idx);
  ushort4 o;
  o.x = f2bf(h.x * dv);
  o.y = f2bf(h.y * dv);
  o.z = f2bf(h.z * dv);
  o.w = f2bf(h.w * dv);
  *reinterpret_cast<ushort4*>(A + idx) = o;
}

// ------- kernel 3: Bt_bf16[j][e] = bf16(W_e * invDE_HT[e][j] * d_j) -------
__global__ __launch_bounds__(256) void k_makeB(const float* __restrict__ R,
                                               const float* __restrict__ W,
                                               const float* __restrict__ d,
                                               unsigned short* __restrict__ Bt) {
  __shared__ float tile[32][33];
  const int j0 = blockIdx.x * 32;
  const int e0 = blockIdx.y * 32;
  const int tx = threadIdx.x;
  const int ty = threadIdx.y;
#pragma unroll
  for (int i = 0; i < 32; i += 8)
    tile[ty + i][tx] = R[(size_t)(e0 + ty + i) * N_DIM + j0 + tx];
  __syncthreads();
  const float we = W[e0 + tx];
#pragma unroll
  for (int i = 0; i < 32; i += 8) {
    const int j = j0 + ty + i;
    float v = tile[tx][ty + i] * we * d[j];
    Bt[(size_t)j * E_DIM + e0 + tx] = f2bf(v);
  }
}

// ---------------- kernel 4: 256x256 8-phase MFMA GEMM, C = A @ B^T ----------------
// 512 threads (8 waves), BK=64, 128 KB LDS double-buffered, XOR-swizzled,
// counted vmcnt(4) per K-tile, setprio around MFMA clusters.

__device__ __forceinline__ void read_af(const unsigned short* base, const int (&off)[2][2],
                                        short8 (&af)[2][2]) {
#pragma unroll
  for (int m = 0; m < 2; ++m)
#pragma unroll
    for (int k = 0; k < 2; ++k)
      af[m][k] = *(const short8*)(base + off[m][k]);
}

__device__ __forceinline__ void read_bf(const unsigned short* base, const int (&off)[4][2],
                                        short8 (&bf)[4][2]) {
#pragma unroll
  for (int n = 0; n < 4; ++n)
#pragma unroll
    for (int k = 0; k < 2; ++k)
      bf[n][k] = *(const short8*)(base + off[n][k]);
}

__device__ __forceinline__ void mfma_quad(f32x4 (&acc)[2][4], const short8 (&af)[2][2],
                                          const short8 (&bf)[4][2]) {
#pragma unroll
  for (int m = 0; m < 2; ++m)
#pragma unroll
    for (int n = 0; n < 4; ++n)
#pragma unroll
      for (int k = 0; k < 2; ++k)
        acc[m][n] = __builtin_amdgcn_mfma_f32_16x16x32_bf16(af[m][k], bf[n][k], acc[m][n], 0, 0, 0);
}

__global__ __launch_bounds__(512, 2) void k_gemm(const unsigned short* __restrict__ A,
                                                 const unsigned short* __restrict__ B,
                                                 float* __restrict__ C) {
  __shared__ unsigned short lds[65536];  // 128 KB: A [0,32768), B [32768,65536)

  const int bid   = blockIdx.x;          // 1024 blocks, %8==0 -> bijective swizzle
  const int chunk = gridDim.x >> 3;
  const int swz   = (bid & 7) * chunk + (bid >> 3);
  const int tm = swz >> 5, tn = swz & 31;
  const size_t rowBase = (size_t)tm * 256;
  const size_t colBase = (size_t)tn * 256;

  const int t = threadIdx.x, wid = t >> 6, lane = t & 63;
  const int lr = lane & 15, hi = lane >> 4;
  const int swzx = (lr & 7) << 4;

  // staging source pointers: LDS dest linear, global source pre-swizzled (rule #21)
  const unsigned short *pa0[2], *pa1[2], *pb0[2], *pb1[2];
#pragma unroll
  for (int j = 0; j < 2; ++j) {
    const int P  = j * 8192 + wid * 1024 + lane * 16;  // physical byte off in 16KB half
    const int rP = P >> 7;
    const int L  = P ^ ((rP & 7) << 4);                // logical byte off (involution)
    const int ce = (L & 127) >> 1;                     // element col
    pa0[j] = A + (rowBase +       rP) * E_DIM + ce;
    pa1[j] = A + (rowBase + 128 + rP) * E_DIM + ce;
    pb0[j] = B + (colBase +       rP) * E_DIM + ce;
    pb1[j] = B + (colBase + 128 + rP) * E_DIM + ce;
  }
  const int dst = wid * 512;  // shorts; + j*4096 + half-base

#define STG(Pj, base_, kt)                                        \
  do {                                                            \
    async16(Pj[0] + (size_t)(kt) * 64, &lds[(base_) + dst]);      \
    async16(Pj[1] + (size_t)(kt) * 64, &lds[(base_) + 4096 + dst]); \
  } while (0)

  // fragment read offsets (shorts), swizzled
  int offA[2][2], offB[4][2];
#pragma unroll
  for (int m = 0; m < 2; ++m)
#pragma unroll
    for (int k = 0; k < 2; ++k) {
      const int row  = (wid & 3) * 32 + m * 16 + lr;
      const int colb = k * 64 + hi * 16;
      offA[m][k] = (row * 128 + (colb ^ swzx)) >> 1;
    }
#pragma unroll
  for (int n = 0; n < 4; ++n)
#pragma unroll
    for (int k = 0; k < 2; ++k) {
      const int row  = (wid >> 2) * 64 + n * 16 + lr;
      const int colb = k * 64 + hi * 16;
      offB[n][k] = (row * 128 + (colb ^ swzx)) >> 1;
    }

  // ---- prologue: tile0 (A0,B0,A1,B1)->buf0, tile1 (A0,B1)->buf1; wait tile0 ----
  STG(pa0, 0, 0);
  STG(pb0, 32768, 0);
  STG(pa1, 8192, 0);
  STG(pb1, 32768 + 8192, 0);
  STG(pa0, 16384, 1);
  STG(pb1, 32768 + 16384 + 8192, 1);
  asm volatile("s_waitcnt vmcnt(4)" ::: "memory");
  __builtin_amdgcn_s_barrier();

  f32x4 acc[2][2][2][4] = {};  // [a][b][m][n]
  short8 af[2][2], bf[4][2];

  for (int T = 0; T < NT; ++T) {
    const int c  = T & 1;
    const int aB = c * 16384;
    const int bB = 32768 + c * 16384;
    const int cN = (T + 1) & 1;
    const int aN = cN * 16384;
    const int bN = 32768 + cN * 16384;

    // ---- phase 0: Q(0,0) — read af(A0)+bf(B0); issue A1(T+1) ----
    read_af(&lds[aB], offA, af);
    read_bf(&lds[bB], offB, bf);
    if (T + 1 < NT) STG(pa1, aN + 8192, T + 1);
    __builtin_amdgcn_s_barrier();
    __builtin_amdgcn_s_setprio(1);
    mfma_quad(acc[0][0], af, bf);
    __builtin_amdgcn_s_setprio(0);
    __builtin_amdgcn_s_barrier();

    // ---- phase 1: Q(0,1) — read bf(B1), reuse af; issue B0(T+1) ----
    read_bf(&lds[bB + 8192], offB, bf);
    if (T + 1 < NT) STG(pb0, bN, T + 1);
    __builtin_amdgcn_s_barrier();
    __builtin_amdgcn_s_setprio(1);
    mfma_quad(acc[0][1], af, bf);
    __builtin_amdgcn_s_setprio(0);
    __builtin_amdgcn_s_barrier();

    // ---- phase 2: Q(1,1) — read af(A1), reuse bf; issue A0(T+2) ----
    read_af(&lds[aB + 8192], offA, af);
    if (T + 2 < NT) STG(pa0, aB, T + 2);
    __builtin_amdgcn_s_barrier();
    __builtin_amdgcn_s_setprio(1);
    mfma_quad(acc[1][1], af, bf);
    __builtin_amdgcn_s_setprio(0);
    __builtin_amdgcn_s_barrier();

    // ---- phase 3: Q(1,0) — read bf(B0), reuse af; issue B1(T+2) ----
    read_bf(&lds[bB], offB, bf);
    if (T + 2 < NT) STG(pb1, bB + 8192, T + 2);
    __builtin_amdgcn_s_barrier();
    __builtin_amdgcn_s_setprio(1);
    mfma_quad(acc[1][0], af, bf);
    __builtin_amdgcn_s_setprio(0);
    // boundary: counted vmcnt guarantees tile T+1 fully landed; never 0 in steady state
    if (T + 2 < NT) {
      asm volatile("s_waitcnt vmcnt(4)" ::: "memory");
    } else if (T + 2 == NT) {
      asm volatile("s_waitcnt vmcnt(0)" ::: "memory");
    }
    __builtin_amdgcn_s_barrier();
  }
#undef STG

  // ---- epilogue: C/D layout col=lane&15, row=(lane>>4)*4+reg ----
#pragma unroll
  for (int a = 0; a < 2; ++a)
#pragma unroll
    for (int b = 0; b < 2; ++b)
#pragma unroll
      for (int m = 0; m < 2; ++m)
#pragma unroll
        for (int n = 0; n < 4; ++n)
#pragma unroll
          for (int r = 0; r < 4; ++r) {
            const size_t row = rowBase + a * 128 + (wid & 3) * 32 + m * 16 + hi * 4 + r;
            const size_t col = colBase + b * 128 + (wid >> 2) * 64 + n * 16 + lr;
            C[row * N_DIM + col] = acc[a][b][m][n][r];
          }
}

extern "C" void kernel_launch(void* const* d_in, const int* in_sizes, int n_in,
                              void* d_out, int out_size, void* d_ws, size_t ws_size,
                              hipStream_t stream) {
  const float* H = (const float*)d_in[0];   // [N, E]
  const float* R = (const float*)d_in[1];   // [E, N]
  const float* W = (const float*)d_in[2];   // [E]
  float* C = (float*)d_out;                 // [N, N]

  char* ws = (char*)d_ws;
  float* d            = (float*)ws;
  unsigned short* Abf = (unsigned short*)(ws + 32768);
  unsigned short* Bbf = (unsigned short*)(ws + 32768 + (size_t)N_DIM * E_DIM * 2);

  k_rowdeg<<<N_DIM / 4, 256, 0, stream>>>(H, W, d);
  k_makeA<<<(int)(((size_t)N_DIM * E_DIM / 4) / 256), 256, 0, stream>>>(H, d, Abf);
  k_makeB<<<dim3(N_DIM / 32, E_DIM / 32), dim3(32, 8), 0, stream>>>(R, W, d, Bbf);
  k_gemm<<<(N_DIM / 256) * (N_DIM / 256), 512, 0, stream>>>(Abf, Bbf, C);
}

// Round 3
// 561.670 us; speedup vs baseline: 1.6671x; 1.0350x over previous
//
#include <hip/hip_runtime.h>

#define N_DIM 8192
#define E_DIM 4096
#define NT    64   // K-tiles of 64

using short8 = __attribute__((ext_vector_type(8))) short;
using f32x4  = __attribute__((ext_vector_type(4))) float;

__device__ __forceinline__ unsigned short f2bf(float f) {
  union { float f; unsigned int u; } v; v.f = f;
  unsigned int r = v.u + 0x7FFFu + ((v.u >> 16) & 1u);
  return (unsigned short)(r >> 16);
}

__device__ __forceinline__ void async16(const void* g, void* l) {
  __builtin_amdgcn_global_load_lds(
      (const __attribute__((address_space(1))) unsigned int*)g,
      (__attribute__((address_space(3))) unsigned int*)l, 16, 0, 0);
}

// ---------------- kernel 1: d = rsqrt(H @ W), one wave per row ----------------
__global__ __launch_bounds__(256) void k_rowdeg(const float* __restrict__ H,
                                                const float* __restrict__ W,
                                                float* __restrict__ d) {
  const int row  = blockIdx.x * 4 + (threadIdx.x >> 6);
  const int lane = threadIdx.x & 63;
  const float* hrow = H + (size_t)row * E_DIM;
  float s = 0.f;
  for (int e = lane * 4; e < E_DIM; e += 64 * 4) {
    float4 h = *reinterpret_cast<const float4*>(hrow + e);
    float4 w = *reinterpret_cast<const float4*>(W + e);
    s += h.x * w.x + h.y * w.y + h.z * w.z + h.w * w.w;
  }
#pragma unroll
  for (int off = 32; off; off >>= 1) s += __shfl_down(s, off);
  if (lane == 0) d[row] = rsqrtf(s);
}

// ---------------- kernel 2: A_bf16[i][e] = bf16(d_i * H[i][e]) ----------------
__global__ __launch_bounds__(256) void k_makeA(const float* __restrict__ H,
                                               const float* __restrict__ d,
                                               unsigned short* __restrict__ A) {
  const size_t idx = ((size_t)blockIdx.x * 256 + threadIdx.x) * 4;
  const int row = (int)(idx >> 12);
  const float dv = d[row];
  float4 h = *reinterpret_cast<const float4*>(H + idx);
  ushort4 o;
  o.x = f2bf(h.x * dv);
  o.y = f2bf(h.y * dv);
  o.z = f2bf(h.z * dv);
  o.w = f2bf(h.w * dv);
  *reinterpret_cast<ushort4*>(A + idx) = o;
}

// ------- kernel 3: Bt_bf16[j][e] = bf16(W_e * invDE_HT[e][j] * d_j) -------
__global__ __launch_bounds__(256) void k_makeB(const float* __restrict__ R,
                                               const float* __restrict__ W,
                                               const float* __restrict__ d,
                                               unsigned short* __restrict__ Bt) {
  __shared__ float tile[32][33];
  const int j0 = blockIdx.x * 32;
  const int e0 = blockIdx.y * 32;
  const int tx = threadIdx.x;
  const int ty = threadIdx.y;
#pragma unroll
  for (int i = 0; i < 32; i += 8)
    tile[ty + i][tx] = R[(size_t)(e0 + ty + i) * N_DIM + j0 + tx];
  __syncthreads();
  const float we = W[e0 + tx];
#pragma unroll
  for (int i = 0; i < 32; i += 8) {
    const int j = j0 + ty + i;
    float v = tile[tx][ty + i] * we * d[j];
    Bt[(size_t)j * E_DIM + e0 + tx] = f2bf(v);
  }
}

// ---------------- kernel 4: 256x256 MFMA GEMM, C = A @ B^T ----------------
// 512 threads (8 waves), BK=64, 128 KB LDS double-buffered, XOR-swizzled.
// 1 barrier per phase: [reads; STG; {vmcnt@p3}; barrier; MFMA] — cross-wave
// overlap of LDS reads with MFMA. STG clobber safety re-derived for 1-barrier
// (every staged region's last reader is >=2 barriers before the issue point).

__device__ __forceinline__ void read_af(const unsigned short* base, const int (&off)[2][2],
                                        short8 (&af)[2][2]) {
#pragma unroll
  for (int m = 0; m < 2; ++m)
#pragma unroll
    for (int k = 0; k < 2; ++k)
      af[m][k] = *(const short8*)(base + off[m][k]);
}

__device__ __forceinline__ void read_bf(const unsigned short* base, const int (&off)[4][2],
                                        short8 (&bf)[4][2]) {
#pragma unroll
  for (int n = 0; n < 4; ++n)
#pragma unroll
    for (int k = 0; k < 2; ++k)
      bf[n][k] = *(const short8*)(base + off[n][k]);
}

__device__ __forceinline__ void mfma_quad(f32x4 (&acc)[2][4], const short8 (&af)[2][2],
                                          const short8 (&bf)[4][2]) {
#pragma unroll
  for (int m = 0; m < 2; ++m)
#pragma unroll
    for (int n = 0; n < 4; ++n)
#pragma unroll
      for (int k = 0; k < 2; ++k)
        acc[m][n] = __builtin_amdgcn_mfma_f32_16x16x32_bf16(af[m][k], bf[n][k], acc[m][n], 0, 0, 0);
}

__global__ __launch_bounds__(512, 2) void k_gemm(const unsigned short* __restrict__ A,
                                                 const unsigned short* __restrict__ B,
                                                 float* __restrict__ C) {
  __shared__ unsigned short lds[65536];  // 128 KB: A [0,32768), B [32768,65536)

  const int bid   = blockIdx.x;          // 1024 blocks, %8==0 -> bijective swizzle
  const int chunk = gridDim.x >> 3;
  const int swz   = (bid & 7) * chunk + (bid >> 3);
  const int tm = swz >> 5, tn = swz & 31;
  const size_t rowBase = (size_t)tm * 256;
  const size_t colBase = (size_t)tn * 256;

  const int t = threadIdx.x, wid = t >> 6, lane = t & 63;
  const int lr = lane & 15, hi = lane >> 4;
  const int swzx = (lr & 7) << 4;

  // staging source pointers: LDS dest linear, global source pre-swizzled (rule #21)
  const unsigned short *pa0[2], *pa1[2], *pb0[2], *pb1[2];
#pragma unroll
  for (int j = 0; j < 2; ++j) {
    const int P  = j * 8192 + wid * 1024 + lane * 16;  // physical byte off in 16KB half
    const int rP = P >> 7;
    const int L  = P ^ ((rP & 7) << 4);                // logical byte off (involution)
    const int ce = (L & 127) >> 1;                     // element col
    pa0[j] = A + (rowBase +       rP) * E_DIM + ce;
    pa1[j] = A + (rowBase + 128 + rP) * E_DIM + ce;
    pb0[j] = B + (colBase +       rP) * E_DIM + ce;
    pb1[j] = B + (colBase + 128 + rP) * E_DIM + ce;
  }
  const int dst = wid * 512;  // shorts; + j*4096 + half-base

#define STG(Pj, base_, kt)                                          \
  do {                                                              \
    async16(Pj[0] + (size_t)(kt) * 64, &lds[(base_) + dst]);        \
    async16(Pj[1] + (size_t)(kt) * 64, &lds[(base_) + 4096 + dst]); \
  } while (0)

  // fragment read offsets (shorts), swizzled
  int offA[2][2], offB[4][2];
#pragma unroll
  for (int m = 0; m < 2; ++m)
#pragma unroll
    for (int k = 0; k < 2; ++k) {
      const int row  = (wid & 3) * 32 + m * 16 + lr;
      const int colb = k * 64 + hi * 16;
      offA[m][k] = (row * 128 + (colb ^ swzx)) >> 1;
    }
#pragma unroll
  for (int n = 0; n < 4; ++n)
#pragma unroll
    for (int k = 0; k < 2; ++k) {
      const int row  = (wid >> 2) * 64 + n * 16 + lr;
      const int colb = k * 64 + hi * 16;
      offB[n][k] = (row * 128 + (colb ^ swzx)) >> 1;
    }

  // ---- prologue: tile0 (A0,B0,A1,B1)->buf0, tile1 (A0,B1)->buf1; wait tile0 ----
  STG(pa0, 0, 0);
  STG(pb0, 32768, 0);
  STG(pa1, 8192, 0);
  STG(pb1, 32768 + 8192, 0);
  STG(pa0, 16384, 1);
  STG(pb1, 32768 + 16384 + 8192, 1);
  asm volatile("s_waitcnt vmcnt(4)" ::: "memory");
  __builtin_amdgcn_s_barrier();

  f32x4 acc[2][2][2][4] = {};  // [a][b][m][n]
  short8 af[2][2], bf[4][2];

  for (int T = 0; T < NT; ++T) {
    const int c  = T & 1;
    const int aB = c * 16384;
    const int bB = 32768 + c * 16384;
    const int cN = (T + 1) & 1;
    const int aN = cN * 16384;
    const int bN = 32768 + cN * 16384;

    // ---- phase 0: Q(0,0) — read af(A0)+bf(B0); issue A1(T+1) ----
    read_af(&lds[aB], offA, af);
    read_bf(&lds[bB], offB, bf);
    if (T + 1 < NT) STG(pa1, aN + 8192, T + 1);
    __builtin_amdgcn_s_barrier();
    __builtin_amdgcn_s_setprio(1);
    mfma_quad(acc[0][0], af, bf);
    __builtin_amdgcn_s_setprio(0);

    // ---- phase 1: Q(0,1) — read bf(B1), reuse af; issue B0(T+1) ----
    read_bf(&lds[bB + 8192], offB, bf);
    if (T + 1 < NT) STG(pb0, bN, T + 1);
    __builtin_amdgcn_s_barrier();
    __builtin_amdgcn_s_setprio(1);
    mfma_quad(acc[0][1], af, bf);
    __builtin_amdgcn_s_setprio(0);

    // ---- phase 2: Q(1,1) — read af(A1), reuse bf; issue A0(T+2) ----
    read_af(&lds[aB + 8192], offA, af);
    if (T + 2 < NT) STG(pa0, aB, T + 2);
    __builtin_amdgcn_s_barrier();
    __builtin_amdgcn_s_setprio(1);
    mfma_quad(acc[1][1], af, bf);
    __builtin_amdgcn_s_setprio(0);

    // ---- phase 3: Q(1,0) — read bf(B0), reuse af; issue B1(T+2) ----
    read_bf(&lds[bB], offB, bf);
    if (T + 2 < NT) STG(pb1, bB + 8192, T + 2);
    // tile gate: counted vmcnt BEFORE the phase barrier — after this barrier,
    // every wave's T+1 stages have landed; never drains to 0 in steady state
    if (T + 2 < NT) {
      asm volatile("s_waitcnt vmcnt(4)" ::: "memory");
    } else if (T + 2 == NT) {
      asm volatile("s_waitcnt vmcnt(0)" ::: "memory");
    }
    __builtin_amdgcn_s_barrier();
    __builtin_amdgcn_s_setprio(1);
    mfma_quad(acc[1][0], af, bf);
    __builtin_amdgcn_s_setprio(0);
  }
#undef STG

  // ---- epilogue: C/D layout col=lane&15, row=(lane>>4)*4+reg ----
#pragma unroll
  for (int a = 0; a < 2; ++a)
#pragma unroll
    for (int b = 0; b < 2; ++b)
#pragma unroll
      for (int m = 0; m < 2; ++m)
#pragma unroll
        for (int n = 0; n < 4; ++n)
#pragma unroll
          for (int r = 0; r < 4; ++r) {
            const size_t row = rowBase + a * 128 + (wid & 3) * 32 + m * 16 + hi * 4 + r;
            const size_t col = colBase + b * 128 + (wid >> 2) * 64 + n * 16 + lr;
            C[row * N_DIM + col] = acc[a][b][m][n][r];
          }
}

extern "C" void kernel_launch(void* const* d_in, const int* in_sizes, int n_in,
                              void* d_out, int out_size, void* d_ws, size_t ws_size,
                              hipStream_t stream) {
  const float* H = (const float*)d_in[0];   // [N, E]
  const float* R = (const float*)d_in[1];   // [E, N]
  const float* W = (const float*)d_in[2];   // [E]
  float* C = (float*)d_out;                 // [N, N]

  char* ws = (char*)d_ws;
  float* d            = (float*)ws;
  unsigned short* Abf = (unsigned short*)(ws + 32768);
  unsigned short* Bbf = (unsigned short*)(ws + 32768 + (size_t)N_DIM * E_DIM * 2);

  k_rowdeg<<<N_DIM / 4, 256, 0, stream>>>(H, W, d);
  k_makeA<<<(int)(((size_t)N_DIM * E_DIM / 4) / 256), 256, 0, stream>>>(H, d, Abf);
  k_makeB<<<dim3(N_DIM / 32, E_DIM / 32), dim3(32, 8), 0, stream>>>(R, W, d, Bbf);
  k_gemm<<<(N_DIM / 256) * (N_DIM / 256), 512, 0, stream>>>(Abf, Bbf, C);
}